// Round 3
// baseline (693.774 us; speedup 1.0000x reference)
//
#include <hip/hip_runtime.h>
#include <hip/hip_bf16.h>
#include <cstdint>

#define NBLK 1024      // graphs
#define NPG  128       // nodes per graph
#define EPG  512       // edges per graph
#define DD   64        // feature dim
#define NSTEP 5        // MAX_STEPS + 1
#define ETOT (NBLK*EPG)
#define NEGF (-1e30f)

// output element offsets (fp32 elements)
#define OA  0                       // actions_seq [B,S]
#define OLS 5120                    // log_pf sum [B]
#define OPF 6144                    // log_pf_steps [B,S]
#define OPB 11264                   // log_pb_steps [B,S]
#define OU  16384                   // used [E]
#define OSN 540672                  // stop nodes [B]
#define OST 541696                  // steps [B]

struct KeysArg {
  uint32_t ke0[NSTEP], ke1[NSTEP];  // edge-gumbel keys per step
  uint32_t ks0[NSTEP], ks1[NSTEP];  // stop-gumbel keys per step
};

__host__ __device__ inline uint32_t rotl32(uint32_t x, int r){ return (x<<r)|(x>>(32-r)); }

// JAX threefry2x32 (20 rounds), bit-exact
__host__ __device__ inline void tf2x32(uint32_t k0, uint32_t k1, uint32_t& x0, uint32_t& x1){
  uint32_t k2 = k0 ^ k1 ^ 0x1BD11BDAu;
  x0 += k0; x1 += k1;
  x0+=x1; x1=rotl32(x1,13); x1^=x0;
  x0+=x1; x1=rotl32(x1,15); x1^=x0;
  x0+=x1; x1=rotl32(x1,26); x1^=x0;
  x0+=x1; x1=rotl32(x1, 6); x1^=x0;
  x0+=k1; x1+=k2+1u;
  x0+=x1; x1=rotl32(x1,17); x1^=x0;
  x0+=x1; x1=rotl32(x1,29); x1^=x0;
  x0+=x1; x1=rotl32(x1,16); x1^=x0;
  x0+=x1; x1=rotl32(x1,24); x1^=x0;
  x0+=k2; x1+=k0+2u;
  x0+=x1; x1=rotl32(x1,13); x1^=x0;
  x0+=x1; x1=rotl32(x1,15); x1^=x0;
  x0+=x1; x1=rotl32(x1,26); x1^=x0;
  x0+=x1; x1=rotl32(x1, 6); x1^=x0;
  x0+=k0; x1+=k1+3u;
  x0+=x1; x1=rotl32(x1,17); x1^=x0;
  x0+=x1; x1=rotl32(x1,29); x1^=x0;
  x0+=x1; x1=rotl32(x1,16); x1^=x0;
  x0+=x1; x1=rotl32(x1,24); x1^=x0;
  x0+=k1; x1+=k2+4u;
  x0+=x1; x1=rotl32(x1,13); x1^=x0;
  x0+=x1; x1=rotl32(x1,15); x1^=x0;
  x0+=x1; x1=rotl32(x1,26); x1^=x0;
  x0+=x1; x1=rotl32(x1, 6); x1^=x0;
  x0+=k2; x1+=k0+5u;
}

// JAX uniform(minval=tiny, maxval=1) -> gumbel, bit-faithful
__device__ inline float gumbel_from_bits(uint32_t bits){
  float f = __uint_as_float((bits>>9) | 0x3f800000u) - 1.0f;   // [0,1)
  const float tiny = 1.17549435e-38f;
  float u = fmaxf(tiny, f * (1.0f - tiny) + tiny);
  return -logf(-logf(u));
}

// JAX partitionable threefry (default since 0.4.36):
// bits[idx] of a 32-bit draw = xor-fold of threefry block at counter (hi=0, lo=idx)
__device__ inline float gumbel_part(uint32_t k0, uint32_t k1, uint32_t idx){
  uint32_t x0 = 0u, x1 = idx;
  tf2x32(k0, k1, x0, x1);
  return gumbel_from_bits(x0 ^ x1);
}

// full-wave (64-lane) sum; identical value on all lanes, deterministic order
__device__ inline float wsum(float x){
  #pragma unroll
  for (int off = 32; off; off >>= 1) x += __shfl_xor(x, off, 64);
  return x;
}

__global__ void __launch_bounds__(64)
gfn_fused(const float* __restrict__ node_tokens,
          const float* __restrict__ edge_emb,
          const float* __restrict__ Wf1, const float* __restrict__ Wnf, const float* __restrict__ Wf2,
          const float* __restrict__ bf,  const float* __restrict__ wf,
          const float* __restrict__ Wb1, const float* __restrict__ Wnb, const float* __restrict__ Wb2,
          const float* __restrict__ bb,  const float* __restrict__ wb,
          const float* __restrict__ w_stop, const float* __restrict__ b_stop,
          const float* __restrict__ Ws,  const float* __restrict__ Wu, const float* __restrict__ bu,
          const int* __restrict__ e_src, const int* __restrict__ e_dst,
          float* __restrict__ out, KeysArg keys)
{
  const int g = blockIdx.x;
  const int lane = threadIdx.x;
  const int ebase = g * EPG;

  __shared__ int s_srcL[EPG];      // local src per edge
  __shared__ int s_dstL[EPG];      // local dst per edge
  __shared__ uint16_t listO[EPG];  // CSR out-edge lists (local edge ids)
  __shared__ uint16_t listI[EPG];  // CSR in-edge lists
  __shared__ int cntO[NPG], cntI[NPG], begO[NPG], begI[NPG];
  __shared__ unsigned char usedL[EPG];
  __shared__ float st[DD];         // state vector
  __shared__ float vrow[DD];       // staging for matvec input rows
  __shared__ float xc[EPG];        // per-candidate scores

  // ---- load edges, init ----
  for (int j = lane; j < EPG; j += 64){
    s_srcL[j] = e_src[ebase+j] - g*NPG;
    s_dstL[j] = e_dst[ebase+j] - g*NPG;
    usedL[j] = 0;
  }
  for (int n = lane; n < NPG; n += 64){ cntO[n]=0; cntI[n]=0; }
  if (lane < DD) st[lane] = 0.f;
  __syncthreads();

  // ---- build per-node CSR adjacency (counted, prefix-summed, then sorted) ----
  for (int j = lane; j < EPG; j += 64){
    atomicAdd(&cntO[s_srcL[j]], 1);
    atomicAdd(&cntI[s_dstL[j]], 1);
  }
  __syncthreads();
  if (lane == 0){
    int a=0, b=0;
    for (int n=0; n<NPG; n++){ begO[n]=a; a+=cntO[n]; begI[n]=b; b+=cntI[n]; }
  }
  __syncthreads();
  for (int n = lane; n < NPG; n += 64){ cntO[n]=0; cntI[n]=0; }
  __syncthreads();
  for (int j = lane; j < EPG; j += 64){
    int sL = s_srcL[j]; int p = atomicAdd(&cntO[sL],1); listO[begO[sL]+p] = (uint16_t)j;
    int dL = s_dstL[j]; int q = atomicAdd(&cntI[dL],1); listI[begI[dL]+q] = (uint16_t)j;
  }
  __syncthreads();
  for (int n = lane; n < NPG; n += 64){
    { int b0=begO[n], c=cntO[n];
      for (int i=1;i<c;i++){ uint16_t v=listO[b0+i]; int j=i-1;
        while (j>=0 && listO[b0+j]>v){ listO[b0+j+1]=listO[b0+j]; j--; } listO[b0+j+1]=v; } }
    { int b0=begI[n], c=cntI[n];
      for (int i=1;i<c;i++){ uint16_t v=listI[b0+i]; int j=i-1;
        while (j>=0 && listI[b0+j]>v){ listI[b0+j+1]=listI[b0+j]; j--; } listI[b0+j+1]=v; } }
  }
  __syncthreads();

  // per-lane copies of small vectors
  const float bf_l = bf[lane], wf_l = wf[lane];
  const float bb_l = bb[lane], wb_l = wb[lane];
  const float bu_l = bu[lane], wst_l = w_stop[lane];
  const float bstop = b_stop[0];

  // wave-uniform rollout state (replicated in registers)
  bool done = false;
  int stepsC = 0;
  int stopn = -1;
  int activeL = 0;          // start node = local 0
  float lpf_sum = 0.f;

  for (int s = 0; s < NSTEP; s++){
    float act_out, lpf_out, lpb_out;
    if (done){
      act_out = -1.f; lpf_out = 0.f; lpb_out = 0.f;
    } else {
      // u_f = state @ Wf2  (per-lane output column)
      float u_j = 0.f;
      #pragma unroll
      for (int i=0;i<DD;i++) u_j = fmaf(st[i], Wf2[i*DD+lane], u_j);
      // nt_f = node_tokens[active] @ Wnf
      const float* ntrow = node_tokens + (size_t)(g*NPG + activeL)*DD;
      vrow[lane] = ntrow[lane];
      __syncthreads();
      float nt_j = 0.f;
      #pragma unroll
      for (int i=0;i<DD;i++) nt_j = fmaf(vrow[i], Wnf[i*DD+lane], nt_j);
      __syncthreads();
      // stop logit
      float sl = wsum(st[lane]*wst_l) + bstop;

      // ---- forward candidates: out-edges of active, not used ----
      const int bO = begO[activeL], dO = cntO[activeL];
      float m1 = NEGF; int nvalid = 0;
      for (int k=0;k<dO;k++){
        int el = listO[bO+k];
        float x = NEGF;
        if (!usedL[el]){
          const float* ee = edge_emb + (size_t)(ebase+el)*DD;
          vrow[lane] = ee[lane];
          __syncthreads();
          float a = 0.f;
          #pragma unroll
          for (int i=0;i<DD;i++) a = fmaf(vrow[i], Wf1[i*DD+lane], a);
          float h = fmaxf(a + nt_j + bf_l + u_j, 0.f);
          x = wsum(h * wf_l);             // score / T, T=1
          m1 = fmaxf(m1, x);
          nvalid++;
          __syncthreads();
        }
        if (lane==0) xc[k] = x;
      }
      __syncthreads();
      const bool has_edge = nvalid > 0;
      float ssum = 0.f;
      for (int k=0;k<dO;k++){ float xk = xc[k]; if (xk != NEGF) ssum += expf(xk - m1); }
      float lse_e = m1 + logf(fmaxf(ssum, 1e-30f));   // == -1e30 when empty, like ref
      const bool allow_stop = (stepsC < 4);
      float stop_t = allow_stop ? sl : NEGF;
      // Z = logaddexp(lse_e, stop_t)
      float amx = fmaxf(lse_e, stop_t);
      float Z = amx + log1pf(expf(-fabsf(lse_e - stop_t)));

      // ---- gumbel-max selection ----
      float mbest = NEGF; int elbest = -1; float xbest = 0.f;
      for (int k=0;k<dO;k++){
        float xk = xc[k];
        if (xk == NEGF) continue;
        int el = listO[bO+k];
        float gum = gumbel_part(keys.ke0[s], keys.ke1[s], (uint32_t)(ebase+el));
        float se = (xk - Z) + gum;
        if (se > mbest){ mbest = se; elbest = el; xbest = xk; }   // ties -> min index (sorted asc)
      }
      float gs = gumbel_part(keys.ks0[s], keys.ks1[s], (uint32_t)g);
      float ss = allow_stop ? (sl - Z) + gs : NEGF;
      float mcmp = has_edge ? mbest : NEGF;
      const bool choose_stop = (ss > mcmp) || (!has_edge);
      float logp_stop = allow_stop ? (sl - Z) : 0.f;
      const bool take_edge = !choose_stop;

      act_out = choose_stop ? -1.f : (float)(ebase + elbest);
      lpf_out = choose_stop ? logp_stop : (xbest - Z);
      lpb_out = 0.f;
      const bool stopping = choose_stop;
      if (stopping && stopn < 0) stopn = activeL;

      if (take_edge){
        // state update: tanh(st@Ws + rel@Wu + bu)
        const float* rel = edge_emb + (size_t)(ebase+elbest)*DD;
        vrow[lane] = rel[lane];
        __syncthreads();
        float accs = 0.f, accr = 0.f;
        #pragma unroll
        for (int i=0;i<DD;i++){
          accs = fmaf(st[i],   Ws[i*DD+lane], accs);
          accr = fmaf(vrow[i], Wu[i*DD+lane], accr);
        }
        float ns = tanhf(accs + accr + bu_l);
        __syncthreads();
        st[lane] = ns;
        __syncthreads();
        // env step
        activeL = s_dstL[elbest];
        if (lane==0) usedL[elbest] = 1;
        stepsC++;
        // ---- backward policy over in-edges of new active ----
        float ub = 0.f;
        #pragma unroll
        for (int i=0;i<DD;i++) ub = fmaf(st[i], Wb2[i*DD+lane], ub);
        const float* ntb = node_tokens + (size_t)(g*NPG + activeL)*DD;
        vrow[lane] = ntb[lane];
        __syncthreads();
        float ntb_j = 0.f;
        #pragma unroll
        for (int i=0;i<DD;i++) ntb_j = fmaf(vrow[i], Wnb[i*DD+lane], ntb_j);
        __syncthreads();
        const int bI = begI[activeL], dI = cntI[activeL];
        float m2 = NEGF, xb_best = 0.f;
        for (int k=0;k<dI;k++){
          int el = listI[bI+k];
          const float* ee = edge_emb + (size_t)(ebase+el)*DD;
          vrow[lane] = ee[lane];
          __syncthreads();
          float a = 0.f;
          #pragma unroll
          for (int i=0;i<DD;i++) a = fmaf(vrow[i], Wb1[i*DD+lane], a);
          float h = fmaxf(a + ntb_j + bb_l + ub, 0.f);
          float xb = wsum(h * wb_l);       // / TB, TB=1
          if (lane==0) xc[k] = xb;
          m2 = fmaxf(m2, xb);
          if (el == elbest) xb_best = xb;
          __syncthreads();
        }
        float s2 = 0.f;
        for (int k=0;k<dI;k++) s2 += expf(xc[k] - m2);
        float lse_b = m2 + logf(fmaxf(s2, 1e-30f));
        lpb_out = xb_best - lse_b;
      }
      done = done || stopping;
    }

    if (lane == 0){
      out[OA  + g*NSTEP + s] = act_out;
      out[OPF + g*NSTEP + s] = lpf_out;
      out[OPB + g*NSTEP + s] = lpb_out;
    }
    lpf_sum += lpf_out;
    __syncthreads();
  }

  // ---- finalize ----
  if (lane == 0){
    out[OLS + g] = lpf_sum;
    int sn = (stopn < 0) ? activeL : stopn;
    out[OSN + g] = (float)sn;
    out[OST + g] = (float)stepsC;
  }
  for (int j = lane; j < EPG; j += 64)
    out[OU + ebase + j] = usedL[j] ? 1.0f : 0.0f;
}

extern "C" void kernel_launch(void* const* d_in, const int* in_sizes, int n_in,
                              void* d_out, int out_size, void* d_ws, size_t ws_size,
                              hipStream_t stream)
{
  (void)in_sizes; (void)n_in; (void)out_size; (void)d_ws; (void)ws_size;

  // JAX key schedule, threefry_partitionable=True (default since jax 0.4.36):
  // key(42) = (0,42)
  // keys = split(key, 5): keys[s] = threefry(key, counter=(0, s))  -> (y0, y1)
  // (ke, ksn) = split(keys[s]): ke = threefry(keys[s], (0,0)), ksn = threefry(keys[s], (0,1))
  KeysArg K;
  for (uint32_t s = 0; s < NSTEP; s++){
    uint32_t a = 0u, b = s;
    tf2x32(0u, 42u, a, b);            // keys[s] = (a, b)
    uint32_t e0 = 0u, e1 = 0u;
    tf2x32(a, b, e0, e1);             // ke = (e0, e1)
    uint32_t s0 = 0u, s1 = 1u;
    tf2x32(a, b, s0, s1);             // ksn = (s0, s1)
    K.ke0[s] = e0; K.ke1[s] = e1;
    K.ks0[s] = s0; K.ks1[s] = s1;
  }

  const int* eidx = (const int*)d_in[17];
  gfn_fused<<<dim3(NBLK), dim3(64), 0, stream>>>(
      (const float*)d_in[0],  (const float*)d_in[1],
      (const float*)d_in[2],  (const float*)d_in[3],  (const float*)d_in[4],
      (const float*)d_in[5],  (const float*)d_in[6],
      (const float*)d_in[7],  (const float*)d_in[8],  (const float*)d_in[9],
      (const float*)d_in[10], (const float*)d_in[11],
      (const float*)d_in[12], (const float*)d_in[13],
      (const float*)d_in[14], (const float*)d_in[15], (const float*)d_in[16],
      eidx, eidx + ETOT,
      (float*)d_out, K);
}

// Round 4
// 139.696 us; speedup vs baseline: 4.9663x; 4.9663x over previous
//
#include <hip/hip_runtime.h>
#include <hip/hip_bf16.h>
#include <cstdint>

#define NBLK 1024      // graphs
#define NPG  128       // nodes per graph
#define EPG  512       // edges per graph
#define DD   64        // feature dim
#define NSTEP 5        // MAX_STEPS + 1
#define ETOT (NBLK*EPG)
#define NEGF (-1e30f)
#define WAVES 4

// output element offsets (fp32 elements)
#define OA  0                       // actions_seq [B,S]
#define OLS 5120                    // log_pf sum [B]
#define OPF 6144                    // log_pf_steps [B,S]
#define OPB 11264                   // log_pb_steps [B,S]
#define OU  16384                   // used [E]
#define OSN 540672                  // stop nodes [B]
#define OST 541696                  // steps [B]

struct KeysArg {
  uint32_t ke0[NSTEP], ke1[NSTEP];  // edge-gumbel keys per step
  uint32_t ks0[NSTEP], ks1[NSTEP];  // stop-gumbel keys per step
};

__host__ __device__ inline uint32_t rotl32(uint32_t x, int r){ return (x<<r)|(x>>(32-r)); }

// JAX threefry2x32 (20 rounds), bit-exact
__host__ __device__ inline void tf2x32(uint32_t k0, uint32_t k1, uint32_t& x0, uint32_t& x1){
  uint32_t k2 = k0 ^ k1 ^ 0x1BD11BDAu;
  x0 += k0; x1 += k1;
  x0+=x1; x1=rotl32(x1,13); x1^=x0;
  x0+=x1; x1=rotl32(x1,15); x1^=x0;
  x0+=x1; x1=rotl32(x1,26); x1^=x0;
  x0+=x1; x1=rotl32(x1, 6); x1^=x0;
  x0+=k1; x1+=k2+1u;
  x0+=x1; x1=rotl32(x1,17); x1^=x0;
  x0+=x1; x1=rotl32(x1,29); x1^=x0;
  x0+=x1; x1=rotl32(x1,16); x1^=x0;
  x0+=x1; x1=rotl32(x1,24); x1^=x0;
  x0+=k2; x1+=k0+2u;
  x0+=x1; x1=rotl32(x1,13); x1^=x0;
  x0+=x1; x1=rotl32(x1,15); x1^=x0;
  x0+=x1; x1=rotl32(x1,26); x1^=x0;
  x0+=x1; x1=rotl32(x1, 6); x1^=x0;
  x0+=k0; x1+=k1+3u;
  x0+=x1; x1=rotl32(x1,17); x1^=x0;
  x0+=x1; x1=rotl32(x1,29); x1^=x0;
  x0+=x1; x1=rotl32(x1,16); x1^=x0;
  x0+=x1; x1=rotl32(x1,24); x1^=x0;
  x0+=k1; x1+=k2+4u;
  x0+=x1; x1=rotl32(x1,13); x1^=x0;
  x0+=x1; x1=rotl32(x1,15); x1^=x0;
  x0+=x1; x1=rotl32(x1,26); x1^=x0;
  x0+=x1; x1=rotl32(x1, 6); x1^=x0;
  x0+=k2; x1+=k0+5u;
}

// JAX uniform(minval=tiny, maxval=1) -> gumbel, bit-faithful
__device__ inline float gumbel_from_bits(uint32_t bits){
  float f = __uint_as_float((bits>>9) | 0x3f800000u) - 1.0f;   // [0,1)
  const float tiny = 1.17549435e-38f;
  float u = fmaxf(tiny, f * (1.0f - tiny) + tiny);
  return -logf(-logf(u));
}

// JAX partitionable threefry: bits[idx] = xor-fold of block at counter (0, idx)
__device__ inline float gumbel_part(uint32_t k0, uint32_t k1, uint32_t idx){
  uint32_t x0 = 0u, x1 = idx;
  tf2x32(k0, k1, x0, x1);
  return gumbel_from_bits(x0 ^ x1);
}

// full-wave (64-lane) sum; identical value on all lanes, deterministic order
__device__ inline float wsum(float x){
  #pragma unroll
  for (int off = 32; off; off >>= 1) x += __shfl_xor(x, off, 64);
  return x;
}

// column matvec: returns sum_i broadcast(v,i) * W[i*DD+lane].
// 4 accumulators (chain depth 16), partial unroll (16 loads in flight, no spills).
__device__ inline float matvec_col(const float* __restrict__ W, float v, int lane){
  float a0=0.f, a1=0.f, a2=0.f, a3=0.f;
  #pragma unroll 4
  for (int i = 0; i < DD; i += 4){
    a0 = fmaf(__shfl(v, i,   64), W[(i  )*DD+lane], a0);
    a1 = fmaf(__shfl(v, i+1, 64), W[(i+1)*DD+lane], a1);
    a2 = fmaf(__shfl(v, i+2, 64), W[(i+2)*DD+lane], a2);
    a3 = fmaf(__shfl(v, i+3, 64), W[(i+3)*DD+lane], a3);
  }
  return (a0+a1)+(a2+a3);
}

__global__ void __launch_bounds__(256)
gfn_fused(const float* __restrict__ node_tokens,
          const float* __restrict__ edge_emb,
          const float* __restrict__ Wf1, const float* __restrict__ Wnf, const float* __restrict__ Wf2,
          const float* __restrict__ bf,  const float* __restrict__ wf,
          const float* __restrict__ Wb1, const float* __restrict__ Wnb, const float* __restrict__ Wb2,
          const float* __restrict__ bb,  const float* __restrict__ wb,
          const float* __restrict__ w_stop, const float* __restrict__ b_stop,
          const float* __restrict__ Ws,  const float* __restrict__ Wu, const float* __restrict__ bu,
          const int* __restrict__ e_src, const int* __restrict__ e_dst,
          float* __restrict__ out, KeysArg keys)
{
  const int g    = blockIdx.x;
  const int tid  = threadIdx.x;
  const int lane = tid & 63;
  const int wave = tid >> 6;
  const int ebase = g * EPG;

  __shared__ uint8_t  srcL[EPG], dstL[EPG];       // local endpoints (0..127)
  __shared__ uint16_t listO[EPG], listI[EPG];     // CSR lists (ascending edge id)
  __shared__ int cntO[NPG], cntI[NPG], begO[NPG], begI[NPG];
  __shared__ uint8_t usedL[EPG];
  __shared__ float st[DD];                        // state vector
  __shared__ float xc[EPG];                       // per-candidate scores
  __shared__ float gm[EPG];                       // per-candidate gumbels
  __shared__ float sh_xbb;                        // backward score of chosen edge

  // ---- load edges, init ----
  for (int j = tid; j < EPG; j += 256){
    srcL[j] = (uint8_t)(e_src[ebase+j] - g*NPG);
    dstL[j] = (uint8_t)(e_dst[ebase+j] - g*NPG);
    usedL[j] = 0;
  }
  for (int n = tid; n < NPG; n += 256){ cntO[n]=0; cntI[n]=0; }
  if (tid < DD) st[tid] = 0.f;
  __syncthreads();

  // ---- count degrees (parallel) ----
  for (int j = tid; j < EPG; j += 256){
    atomicAdd(&cntO[srcL[j]], 1);
    atomicAdd(&cntI[dstL[j]], 1);
  }
  __syncthreads();

  // ---- exclusive prefix sum via wave-0 shfl scan (2 nodes/lane) ----
  if (wave == 0){
    int n0 = lane*2, n1 = n0+1;
    int c0O=cntO[n0], c1O=cntO[n1], sO=c0O+c1O;
    int c0I=cntI[n0], c1I=cntI[n1], sI=c0I+c1I;
    int xO=sO, xI=sI;
    #pragma unroll
    for (int off=1; off<64; off<<=1){
      int tO=__shfl_up(xO,off,64), tI=__shfl_up(xI,off,64);
      if (lane>=off){ xO+=tO; xI+=tI; }
    }
    begO[n0]=xO-sO; begO[n1]=xO-c1O;
    begI[n0]=xI-sI; begI[n1]=xI-c1I;
  }
  __syncthreads();
  for (int n = tid; n < NPG; n += 256){ cntO[n]=0; cntI[n]=0; }
  __syncthreads();

  // ---- phased fill: wave ph appends its 128-edge range, phases in order ->
  //      lists end up in ascending edge-id order, deterministically ----
  for (int ph = 0; ph < WAVES; ph++){
    if (wave == ph){
      #pragma unroll
      for (int h = 0; h < 2; h++){
        int j = ph*128 + h*64 + lane;
        int sL = srcL[j]; int p = atomicAdd(&cntO[sL],1); listO[begO[sL]+p] = (uint16_t)j;
        int dL = dstL[j]; int q = atomicAdd(&cntI[dL],1); listI[begI[dL]+q] = (uint16_t)j;
      }
    }
    __syncthreads();
  }

  // per-lane copies of small vectors
  const float bf_l = bf[lane], wf_l = wf[lane];
  const float bb_l = bb[lane], wb_l = wb[lane];
  const float bu_l = bu[lane], wst_l = w_stop[lane];
  const float bstop = b_stop[0];

  // block-uniform rollout state (replicated per thread; all updates deterministic)
  bool done = false;
  int stepsC = 0;
  int stopn = -1;
  int activeL = 0;
  float lpf_sum = 0.f;

  for (int s = 0; s < NSTEP; s++){
    float act_out = -1.f, lpf_out = 0.f, lpb_out = 0.f;
    if (!done){
      const int bO = begO[activeL], dO = cntO[activeL];

      // state-dependent vectors (redundant per wave; bitwise identical)
      float st_v = st[lane];
      float u_j  = matvec_col(Wf2, st_v, lane);
      float ntv  = node_tokens[(size_t)(g*NPG + activeL)*DD + lane];
      float nt_j = matvec_col(Wnf, ntv, lane);
      float sl   = wsum(st_v * wst_l) + bstop;

      // ---- wave-parallel forward candidate scoring ----
      for (int k = wave; k < dO; k += WAVES){
        int el = listO[bO+k];
        float x = NEGF, gg = 0.f;
        if (!usedL[el]){
          float ev = edge_emb[(size_t)(ebase+el)*DD + lane];
          float a  = matvec_col(Wf1, ev, lane);
          float h  = fmaxf(a + nt_j + bf_l + u_j, 0.f);
          x  = wsum(h * wf_l);                 // score / T, T=1
          gg = gumbel_part(keys.ke0[s], keys.ke1[s], (uint32_t)(ebase+el));
        }
        if (lane == 0){ xc[k] = x; gm[k] = gg; }
      }
      __syncthreads();

      // ---- combine (redundant on every thread, fixed k order => uniform) ----
      float m1 = NEGF; int nvalid = 0;
      for (int k=0;k<dO;k++){ float xk=xc[k]; if (xk!=NEGF){ m1=fmaxf(m1,xk); nvalid++; } }
      float ssum = 0.f;
      for (int k=0;k<dO;k++){ float xk=xc[k]; if (xk!=NEGF) ssum += expf(xk - m1); }
      const bool has_edge = nvalid > 0;
      float lse_e = m1 + logf(fmaxf(ssum, 1e-30f));
      const bool allow_stop = (stepsC < 4);
      float stop_t = allow_stop ? sl : NEGF;
      float amx = fmaxf(lse_e, stop_t);
      float Z = amx + log1pf(expf(-fabsf(lse_e - stop_t)));

      float mbest = NEGF; int elbest = -1; float xbest = 0.f;
      for (int k=0;k<dO;k++){
        float xk = xc[k];
        if (xk == NEGF) continue;
        float se = (xk - Z) + gm[k];
        if (se > mbest){ mbest = se; elbest = listO[bO+k]; xbest = xk; }
      }
      float gs = gumbel_part(keys.ks0[s], keys.ks1[s], (uint32_t)g);
      float ss = allow_stop ? (sl - Z) + gs : NEGF;
      float mcmp = has_edge ? mbest : NEGF;
      const bool choose_stop = (ss > mcmp) || (!has_edge);
      float logp_stop = allow_stop ? (sl - Z) : 0.f;
      const bool take_edge = !choose_stop;

      act_out = choose_stop ? -1.f : (float)(ebase + elbest);
      lpf_out = choose_stop ? logp_stop : (xbest - Z);
      if (choose_stop && stopn < 0) stopn = activeL;

      // ---- state update (reads old st; barrier before overwrite) ----
      float ns = 0.f;
      if (take_edge){
        float rv = edge_emb[(size_t)(ebase+elbest)*DD + lane];
        float accs = matvec_col(Ws, st_v, lane);
        float accr = matvec_col(Wu, rv,  lane);
        ns = tanhf(accs + accr + bu_l);
      }
      __syncthreads();               // everyone has read old st
      if (take_edge){
        if (tid < DD) st[tid] = ns;  // wave 0 writes
        if (tid == 0) usedL[elbest] = 1;
        activeL = dstL[elbest];
        stepsC++;
      }
      __syncthreads();               // new st / used visible

      // ---- wave-parallel backward scoring over in-edges of new active ----
      if (take_edge){
        float st2 = st[lane];
        float ub    = matvec_col(Wb2, st2, lane);
        float nbv   = node_tokens[(size_t)(g*NPG + activeL)*DD + lane];
        float ntb_j = matvec_col(Wnb, nbv, lane);
        const int bI = begI[activeL], dI = cntI[activeL];
        for (int k = wave; k < dI; k += WAVES){
          int el = listI[bI+k];
          float ev = edge_emb[(size_t)(ebase+el)*DD + lane];
          float a  = matvec_col(Wb1, ev, lane);
          float h  = fmaxf(a + ntb_j + bb_l + ub, 0.f);
          float xb = wsum(h * wb_l);
          if (lane == 0){ xc[k] = xb; if (el == elbest) sh_xbb = xb; }
        }
      }
      __syncthreads();
      if (take_edge){
        const int dI = cntI[activeL];
        float m2 = NEGF;
        for (int k=0;k<dI;k++) m2 = fmaxf(m2, xc[k]);
        float s2 = 0.f;
        for (int k=0;k<dI;k++) s2 += expf(xc[k] - m2);
        float lse_b = m2 + logf(fmaxf(s2, 1e-30f));
        lpb_out = sh_xbb - lse_b;
      }
      done = done || choose_stop;
      __syncthreads();               // xc reuse + st stable before next step
    }

    if (tid == 0){
      out[OA  + g*NSTEP + s] = act_out;
      out[OPF + g*NSTEP + s] = lpf_out;
      out[OPB + g*NSTEP + s] = lpb_out;
    }
    lpf_sum += lpf_out;
  }

  // ---- finalize ----
  if (tid == 0){
    out[OLS + g] = lpf_sum;
    int sn = (stopn < 0) ? activeL : stopn;
    out[OSN + g] = (float)sn;
    out[OST + g] = (float)stepsC;
  }
  for (int j = tid; j < EPG; j += 256)
    out[OU + ebase + j] = usedL[j] ? 1.0f : 0.0f;
}

extern "C" void kernel_launch(void* const* d_in, const int* in_sizes, int n_in,
                              void* d_out, int out_size, void* d_ws, size_t ws_size,
                              hipStream_t stream)
{
  (void)in_sizes; (void)n_in; (void)out_size; (void)d_ws; (void)ws_size;

  // JAX key schedule, threefry_partitionable (default since jax 0.4.36):
  // key(42)=(0,42); keys[s]=tf(key,(0,s)); ke=tf(keys[s],(0,0)), ksn=tf(keys[s],(0,1))
  KeysArg K;
  for (uint32_t s = 0; s < NSTEP; s++){
    uint32_t a = 0u, b = s;
    tf2x32(0u, 42u, a, b);
    uint32_t e0 = 0u, e1 = 0u;
    tf2x32(a, b, e0, e1);
    uint32_t s0 = 0u, s1 = 1u;
    tf2x32(a, b, s0, s1);
    K.ke0[s] = e0; K.ke1[s] = e1;
    K.ks0[s] = s0; K.ks1[s] = s1;
  }

  const int* eidx = (const int*)d_in[17];
  gfn_fused<<<dim3(NBLK), dim3(256), 0, stream>>>(
      (const float*)d_in[0],  (const float*)d_in[1],
      (const float*)d_in[2],  (const float*)d_in[3],  (const float*)d_in[4],
      (const float*)d_in[5],  (const float*)d_in[6],
      (const float*)d_in[7],  (const float*)d_in[8],  (const float*)d_in[9],
      (const float*)d_in[10], (const float*)d_in[11],
      (const float*)d_in[12], (const float*)d_in[13],
      (const float*)d_in[14], (const float*)d_in[15], (const float*)d_in[16],
      eidx, eidx + ETOT,
      (float*)d_out, K);
}

// Round 5
// 111.204 us; speedup vs baseline: 6.2387x; 1.2562x over previous
//
#include <hip/hip_runtime.h>
#include <hip/hip_bf16.h>
#include <cstdint>

#define NBLK 1024      // graphs
#define NPG  128       // nodes per graph
#define EPG  512       // edges per graph
#define DD   64        // feature dim
#define NSTEP 5        // MAX_STEPS + 1
#define ETOT (NBLK*EPG)
#define NEGF (-1e30f)
#define WAVES 4
#define MAXDEG 32      // P(Poisson(4) > 32) ~ 1e-19 per node; safe cap

// output element offsets (fp32 elements)
#define OA  0                       // actions_seq [B,S]
#define OLS 5120                    // log_pf sum [B]
#define OPF 6144                    // log_pf_steps [B,S]
#define OPB 11264                   // log_pb_steps [B,S]
#define OU  16384                   // used [E]
#define OSN 540672                  // stop nodes [B]
#define OST 541696                  // steps [B]

struct KeysArg {
  uint32_t ke0[NSTEP], ke1[NSTEP];  // edge-gumbel keys per step
  uint32_t ks0[NSTEP], ks1[NSTEP];  // stop-gumbel keys per step
};

__host__ __device__ inline uint32_t rotl32(uint32_t x, int r){ return (x<<r)|(x>>(32-r)); }

// JAX threefry2x32 (20 rounds), bit-exact
__host__ __device__ inline void tf2x32(uint32_t k0, uint32_t k1, uint32_t& x0, uint32_t& x1){
  uint32_t k2 = k0 ^ k1 ^ 0x1BD11BDAu;
  x0 += k0; x1 += k1;
  x0+=x1; x1=rotl32(x1,13); x1^=x0;
  x0+=x1; x1=rotl32(x1,15); x1^=x0;
  x0+=x1; x1=rotl32(x1,26); x1^=x0;
  x0+=x1; x1=rotl32(x1, 6); x1^=x0;
  x0+=k1; x1+=k2+1u;
  x0+=x1; x1=rotl32(x1,17); x1^=x0;
  x0+=x1; x1=rotl32(x1,29); x1^=x0;
  x0+=x1; x1=rotl32(x1,16); x1^=x0;
  x0+=x1; x1=rotl32(x1,24); x1^=x0;
  x0+=k2; x1+=k0+2u;
  x0+=x1; x1=rotl32(x1,13); x1^=x0;
  x0+=x1; x1=rotl32(x1,15); x1^=x0;
  x0+=x1; x1=rotl32(x1,26); x1^=x0;
  x0+=x1; x1=rotl32(x1, 6); x1^=x0;
  x0+=k0; x1+=k1+3u;
  x0+=x1; x1=rotl32(x1,17); x1^=x0;
  x0+=x1; x1=rotl32(x1,29); x1^=x0;
  x0+=x1; x1=rotl32(x1,16); x1^=x0;
  x0+=x1; x1=rotl32(x1,24); x1^=x0;
  x0+=k1; x1+=k2+4u;
  x0+=x1; x1=rotl32(x1,13); x1^=x0;
  x0+=x1; x1=rotl32(x1,15); x1^=x0;
  x0+=x1; x1=rotl32(x1,26); x1^=x0;
  x0+=x1; x1=rotl32(x1, 6); x1^=x0;
  x0+=k2; x1+=k0+5u;
}

// JAX uniform(minval=tiny, maxval=1) -> gumbel, bit-faithful
__device__ inline float gumbel_from_bits(uint32_t bits){
  float f = __uint_as_float((bits>>9) | 0x3f800000u) - 1.0f;   // [0,1)
  const float tiny = 1.17549435e-38f;
  float u = fmaxf(tiny, f * (1.0f - tiny) + tiny);
  return -logf(-logf(u));
}

// JAX partitionable threefry: bits[idx] = xor-fold of block at counter (0, idx)
__device__ inline float gumbel_part(uint32_t k0, uint32_t k1, uint32_t idx){
  uint32_t x0 = 0u, x1 = idx;
  tf2x32(k0, k1, x0, x1);
  return gumbel_from_bits(x0 ^ x1);
}

// full-wave (64-lane) sum; identical value on all lanes, deterministic order
__device__ inline float wsum(float x){
  #pragma unroll
  for (int off = 32; off; off >>= 1) x += __shfl_xor(x, off, 64);
  return x;
}

// column matvec: sum_i broadcast(v,i) * W[i*DD+lane]; 4 accs, round-4-identical order
__device__ inline float matvec_col(const float* __restrict__ W, float v, int lane){
  float a0=0.f, a1=0.f, a2=0.f, a3=0.f;
  #pragma unroll 4
  for (int i = 0; i < DD; i += 4){
    a0 = fmaf(__shfl(v, i,   64), W[(i  )*DD+lane], a0);
    a1 = fmaf(__shfl(v, i+1, 64), W[(i+1)*DD+lane], a1);
    a2 = fmaf(__shfl(v, i+2, 64), W[(i+2)*DD+lane], a2);
    a3 = fmaf(__shfl(v, i+3, 64), W[(i+3)*DD+lane], a3);
  }
  return (a0+a1)+(a2+a3);
}

// 4-candidate batched matvec: reads each W row ONCE, accumulates 4 outputs.
// Per-candidate accumulation order bit-identical to matvec_col.
__device__ inline void matvec4(const float* __restrict__ W,
                               float v0, float v1, float v2, float v3,
                               int lane, float o[4]){
  float acc[4][4] = {{0,0,0,0},{0,0,0,0},{0,0,0,0},{0,0,0,0}};
  #pragma unroll 4
  for (int i = 0; i < DD; i += 4){
    #pragma unroll
    for (int t = 0; t < 4; t++){
      float w  = W[(i+t)*DD+lane];
      float b0 = __shfl(v0, i+t, 64);
      float b1 = __shfl(v1, i+t, 64);
      float b2 = __shfl(v2, i+t, 64);
      float b3 = __shfl(v3, i+t, 64);
      acc[0][t] = fmaf(b0, w, acc[0][t]);
      acc[1][t] = fmaf(b1, w, acc[1][t]);
      acc[2][t] = fmaf(b2, w, acc[2][t]);
      acc[3][t] = fmaf(b3, w, acc[3][t]);
    }
  }
  #pragma unroll
  for (int c = 0; c < 4; c++)
    o[c] = (acc[c][0]+acc[c][1])+(acc[c][2]+acc[c][3]);
}

__global__ void __launch_bounds__(256)
gfn_fused(const float* __restrict__ node_tokens,
          const float* __restrict__ edge_emb,
          const float* __restrict__ Wf1, const float* __restrict__ Wnf, const float* __restrict__ Wf2,
          const float* __restrict__ bf,  const float* __restrict__ wf,
          const float* __restrict__ Wb1, const float* __restrict__ Wnb, const float* __restrict__ Wb2,
          const float* __restrict__ bb,  const float* __restrict__ wb,
          const float* __restrict__ w_stop, const float* __restrict__ b_stop,
          const float* __restrict__ Ws,  const float* __restrict__ Wu, const float* __restrict__ bu,
          const int* __restrict__ e_src, const int* __restrict__ e_dst,
          float* __restrict__ out, KeysArg keys)
{
  const int g    = blockIdx.x;
  const int tid  = threadIdx.x;
  const int lane = tid & 63;
  const int wave = tid >> 6;
  const int ebase = g * EPG;

  __shared__ uint8_t  srcL[EPG], dstL[EPG];       // local endpoints (0..127)
  __shared__ uint16_t listO[EPG], listI[EPG];     // CSR lists (ascending edge id)
  __shared__ int cntO[NPG], cntI[NPG], begO[NPG], begI[NPG];
  __shared__ uint8_t usedL[EPG];
  __shared__ float st[DD];                        // state vector
  __shared__ float a_sh[MAXDEG][DD];              // per-candidate pre-activation
  __shared__ float u_sh[DD], nt_sh[DD];           // fwd shared vectors
  __shared__ float ub_sh[DD], ntb_sh[DD];         // bwd shared vectors
  __shared__ float acs_sh[DD], acr_sh[DD];        // state-update partials
  __shared__ float xc[MAXDEG], gm[MAXDEG];        // scores, gumbels
  __shared__ float sl_sh, gs_sh, sh_xbb;

  // ---- load edges, init ----
  for (int j = tid; j < EPG; j += 256){
    srcL[j] = (uint8_t)(e_src[ebase+j] - g*NPG);
    dstL[j] = (uint8_t)(e_dst[ebase+j] - g*NPG);
    usedL[j] = 0;
  }
  for (int n = tid; n < NPG; n += 256){ cntO[n]=0; cntI[n]=0; }
  if (tid < DD) st[tid] = 0.f;
  __syncthreads();

  // ---- count degrees ----
  for (int j = tid; j < EPG; j += 256){
    atomicAdd(&cntO[srcL[j]], 1);
    atomicAdd(&cntI[dstL[j]], 1);
  }
  __syncthreads();

  // ---- exclusive prefix sum via wave-0 shfl scan (2 nodes/lane) ----
  if (wave == 0){
    int n0 = lane*2, n1 = n0+1;
    int c0O=cntO[n0], c1O=cntO[n1], sO=c0O+c1O;
    int c0I=cntI[n0], c1I=cntI[n1], sI=c0I+c1I;
    int xO=sO, xI=sI;
    #pragma unroll
    for (int off=1; off<64; off<<=1){
      int tO=__shfl_up(xO,off,64), tI=__shfl_up(xI,off,64);
      if (lane>=off){ xO+=tO; xI+=tI; }
    }
    begO[n0]=xO-sO; begO[n1]=xO-c1O;
    begI[n0]=xI-sI; begI[n1]=xI-c1I;
  }
  __syncthreads();
  for (int n = tid; n < NPG; n += 256){ cntO[n]=0; cntI[n]=0; }
  __syncthreads();

  // ---- phased fill: ascending edge-id order, deterministic ----
  for (int ph = 0; ph < WAVES; ph++){
    if (wave == ph){
      #pragma unroll
      for (int h = 0; h < 2; h++){
        int j = ph*128 + h*64 + lane;
        int sL = srcL[j]; int p = atomicAdd(&cntO[sL],1); listO[begO[sL]+p] = (uint16_t)j;
        int dL = dstL[j]; int q = atomicAdd(&cntI[dL],1); listI[begI[dL]+q] = (uint16_t)j;
      }
    }
    __syncthreads();
  }

  // per-lane copies of small vectors
  const float bf_l = bf[lane], wf_l = wf[lane];
  const float bb_l = bb[lane], wb_l = wb[lane];
  const float wst_l = w_stop[lane];
  const float bstop = b_stop[0];

  // block-uniform rollout state (replicated per thread)
  bool done = false;
  int stepsC = 0;
  int stopn = -1;
  int activeL = 0;
  float lpf_sum = 0.f;

  for (int s = 0; s < NSTEP; s++){
    float act_out = -1.f, lpf_out = 0.f, lpb_out = 0.f;
    if (!done){
      const int bO = begO[activeL];
      const int dOc = min(cntO[activeL], MAXDEG);
      float st_v = st[lane];

      // ---- P1: specialized concurrent passes ----
      if (wave == 0){                       // u = Wf2^T st
        u_sh[lane] = matvec_col(Wf2, st_v, lane);
      } else if (wave == 1){                // nt = Wnf^T node_tokens[active]
        float ntv = node_tokens[(size_t)(g*NPG + activeL)*DD + lane];
        nt_sh[lane] = matvec_col(Wnf, ntv, lane);
      } else if (wave == 2){                // fwd candidates: a_k = Wf1^T e_k (batched)
        for (int base = 0; base < dOc; base += 4){
          float v[4];
          #pragma unroll
          for (int t = 0; t < 4; t++){
            int k = base + t;
            int el = listO[bO + min(k, dOc-1)];
            v[t] = edge_emb[(size_t)(ebase+el)*DD + lane];
          }
          float o[4];
          matvec4(Wf1, v[0], v[1], v[2], v[3], lane, o);
          #pragma unroll
          for (int t = 0; t < 4; t++){
            int k = base + t;
            if (k < dOc) a_sh[k][lane] = o[t];
          }
        }
      } else {                              // stop logit + all gumbels (lane-parallel)
        float sl = wsum(st_v * wst_l) + bstop;
        if (lane == 0) sl_sh = sl;
        if (lane < dOc){
          int el = listO[bO + lane];
          gm[lane] = gumbel_part(keys.ke0[s], keys.ke1[s], (uint32_t)(ebase+el));
        }
        if (lane == 63) gs_sh = gumbel_part(keys.ks0[s], keys.ks1[s], (uint32_t)g);
      }
      __syncthreads();

      // ---- P2: score epilogue (round-4 add order: ((a+nt)+bf)+u) ----
      for (int k = wave; k < dOc; k += WAVES){
        int el = listO[bO + k];
        float x = NEGF;
        if (!usedL[el]){
          float h = fmaxf(a_sh[k][lane] + nt_sh[lane] + bf_l + u_sh[lane], 0.f);
          x = wsum(h * wf_l);
        }
        if (lane == 0) xc[k] = x;
      }
      __syncthreads();

      // ---- P3: combine + selection (redundant on all threads, block-uniform) ----
      float sl = sl_sh;
      float m1 = NEGF; int nvalid = 0;
      for (int k=0;k<dOc;k++){ float xk=xc[k]; if (xk!=NEGF){ m1=fmaxf(m1,xk); nvalid++; } }
      float ssum = 0.f;
      for (int k=0;k<dOc;k++){ float xk=xc[k]; if (xk!=NEGF) ssum += expf(xk - m1); }
      const bool has_edge = nvalid > 0;
      float lse_e = m1 + logf(fmaxf(ssum, 1e-30f));
      const bool allow_stop = (stepsC < 4);
      float stop_t = allow_stop ? sl : NEGF;
      float amx = fmaxf(lse_e, stop_t);
      float Z = amx + log1pf(expf(-fabsf(lse_e - stop_t)));

      float mbest = NEGF; int elbest = -1; float xbest = 0.f;
      for (int k=0;k<dOc;k++){
        float xk = xc[k];
        if (xk == NEGF) continue;
        float se = (xk - Z) + gm[k];
        if (se > mbest){ mbest = se; elbest = listO[bO+k]; xbest = xk; }
      }
      float ss = allow_stop ? (sl - Z) + gs_sh : NEGF;
      float mcmp = has_edge ? mbest : NEGF;
      const bool choose_stop = (ss > mcmp) || (!has_edge);
      float logp_stop = allow_stop ? (sl - Z) : 0.f;
      const bool take_edge = !choose_stop;

      act_out = choose_stop ? -1.f : (float)(ebase + elbest);
      lpf_out = choose_stop ? logp_stop : (xbest - Z);
      if (choose_stop && stopn < 0) stopn = activeL;

      // ---- P4: state update (w0: Ws^T st, w1: Wu^T rel, concurrent) ----
      if (take_edge){
        if (wave == 0){
          acs_sh[lane] = matvec_col(Ws, st_v, lane);
        } else if (wave == 1){
          float rv = edge_emb[(size_t)(ebase+elbest)*DD + lane];
          acr_sh[lane] = matvec_col(Wu, rv, lane);
        }
      }
      __syncthreads();
      if (take_edge){
        if (tid < DD) st[tid] = tanhf(acs_sh[tid] + acr_sh[tid] + bu[tid]);
        if (tid == 0) usedL[elbest] = 1;
        activeL = dstL[elbest];
        stepsC++;
      }
      __syncthreads();

      // ---- P5: backward passes (w0: Wb2^T st', w1: Wnb^T nt', w2: candidates) ----
      const int bI = begI[activeL];
      const int dIc = take_edge ? min(cntI[activeL], MAXDEG) : 0;
      if (take_edge){
        if (wave == 0){
          ub_sh[lane] = matvec_col(Wb2, st[lane], lane);
        } else if (wave == 1){
          float nbv = node_tokens[(size_t)(g*NPG + activeL)*DD + lane];
          ntb_sh[lane] = matvec_col(Wnb, nbv, lane);
        } else if (wave == 2){
          for (int base = 0; base < dIc; base += 4){
            float v[4];
            #pragma unroll
            for (int t = 0; t < 4; t++){
              int k = base + t;
              int el = listI[bI + min(k, dIc-1)];
              v[t] = edge_emb[(size_t)(ebase+el)*DD + lane];
            }
            float o[4];
            matvec4(Wb1, v[0], v[1], v[2], v[3], lane, o);
            #pragma unroll
            for (int t = 0; t < 4; t++){
              int k = base + t;
              if (k < dIc) a_sh[k][lane] = o[t];
            }
          }
        }
      }
      __syncthreads();

      // ---- P6: backward score epilogue + combine ----
      if (take_edge){
        for (int k = wave; k < dIc; k += WAVES){
          int el = listI[bI + k];
          float h = fmaxf(a_sh[k][lane] + ntb_sh[lane] + bb_l + ub_sh[lane], 0.f);
          float xb = wsum(h * wb_l);
          if (lane == 0){ xc[k] = xb; if (el == elbest) sh_xbb = xb; }
        }
      }
      __syncthreads();
      if (take_edge){
        float m2 = NEGF;
        for (int k=0;k<dIc;k++) m2 = fmaxf(m2, xc[k]);
        float s2 = 0.f;
        for (int k=0;k<dIc;k++) s2 += expf(xc[k] - m2);
        float lse_b = m2 + logf(fmaxf(s2, 1e-30f));
        lpb_out = sh_xbb - lse_b;
      }
      done = done || choose_stop;
      __syncthreads();
    }

    if (tid == 0){
      out[OA  + g*NSTEP + s] = act_out;
      out[OPF + g*NSTEP + s] = lpf_out;
      out[OPB + g*NSTEP + s] = lpb_out;
    }
    lpf_sum += lpf_out;
  }

  // ---- finalize ----
  if (tid == 0){
    out[OLS + g] = lpf_sum;
    int sn = (stopn < 0) ? activeL : stopn;
    out[OSN + g] = (float)sn;
    out[OST + g] = (float)stepsC;
  }
  for (int j = tid; j < EPG; j += 256)
    out[OU + ebase + j] = usedL[j] ? 1.0f : 0.0f;
}

extern "C" void kernel_launch(void* const* d_in, const int* in_sizes, int n_in,
                              void* d_out, int out_size, void* d_ws, size_t ws_size,
                              hipStream_t stream)
{
  (void)in_sizes; (void)n_in; (void)out_size; (void)d_ws; (void)ws_size;

  // JAX key schedule, threefry_partitionable (default since jax 0.4.36):
  // key(42)=(0,42); keys[s]=tf(key,(0,s)); ke=tf(keys[s],(0,0)), ksn=tf(keys[s],(0,1))
  KeysArg K;
  for (uint32_t s = 0; s < NSTEP; s++){
    uint32_t a = 0u, b = s;
    tf2x32(0u, 42u, a, b);
    uint32_t e0 = 0u, e1 = 0u;
    tf2x32(a, b, e0, e1);
    uint32_t s0 = 0u, s1 = 1u;
    tf2x32(a, b, s0, s1);
    K.ke0[s] = e0; K.ke1[s] = e1;
    K.ks0[s] = s0; K.ks1[s] = s1;
  }

  const int* eidx = (const int*)d_in[17];
  gfn_fused<<<dim3(NBLK), dim3(256), 0, stream>>>(
      (const float*)d_in[0],  (const float*)d_in[1],
      (const float*)d_in[2],  (const float*)d_in[3],  (const float*)d_in[4],
      (const float*)d_in[5],  (const float*)d_in[6],
      (const float*)d_in[7],  (const float*)d_in[8],  (const float*)d_in[9],
      (const float*)d_in[10], (const float*)d_in[11],
      (const float*)d_in[12], (const float*)d_in[13],
      (const float*)d_in[14], (const float*)d_in[15], (const float*)d_in[16],
      eidx, eidx + ETOT,
      (float*)d_out, K);
}